// Round 6
// baseline (3675.279 us; speedup 1.0000x reference)
//
#include <hip/hip_runtime.h>
#include <stdint.h>

// 128x128 block tile, 4 waves (256 threads), per-wave 64x64 (proven geometry).
// NEW (round 6): depth-2 software pipeline — double-buffered LDS (2 x 32 KB),
// counted s_waitcnt vmcnt(8) + raw s_barrier so prefetch loads stay in flight
// ACROSS barriers (T3/T4 mechanism). Rounds 1-5 proved MfmaUtil ~23% is
// invariant under all TLP knobs; the binder is the per-iter vmcnt(0) drain
// (~600cy L3-served weight loads, zero cover). Steady-state iter:
//   COMPUTE(buf[i&1]) ; bar ; STAGE(i+2 -> buf[i&1]) ; vmcnt(8) ; bar
// stage(i+1) gets a full compute phase of latency cover; stage(i+2) flies
// through the barrier. vmcnt FIFO: outstanding = stage(i+1)[8]+stage(i+2)[8],
// wait-to-8 drains exactly stage(i+1).
#define BM 128
#define BN 128
#define BK 64
#define NTHREADS 256

typedef __bf16 bf16x8 __attribute__((ext_vector_type(8)));
typedef float f32x4 __attribute__((ext_vector_type(4)));

__device__ __forceinline__ float bf2f(uint16_t u) {
  union { uint32_t u32; float f; } x; x.u32 = ((uint32_t)u) << 16; return x.f;
}
// round-to-nearest-even f32 -> bf16 (finite values only)
__device__ __forceinline__ uint16_t f2bf(float f) {
  uint32_t x = __float_as_uint(f);
  uint32_t r = (x + 0x7FFFu + ((x >> 16) & 1u)) >> 16;
  return (uint16_t)r;
}

// async global->LDS, 16B per lane. LDS dest is wave-uniform base + lane*16B.
__device__ __forceinline__ void gload_lds16(const uint16_t* g, uint16_t* l) {
  __builtin_amdgcn_global_load_lds(
      (const __attribute__((address_space(1))) uint32_t*)g,
      (__attribute__((address_space(3))) uint32_t*)l, 16, 0, 0);
}

// counted waits + raw barrier. sched_barrier(0) pins the phase boundary so
// the scheduler cannot hoist ds_reads/MFMA across the asm wait (rule #18).
__device__ __forceinline__ void waitv8() {
  asm volatile("s_waitcnt vmcnt(8)" ::: "memory");
  __builtin_amdgcn_sched_barrier(0);
}
__device__ __forceinline__ void waitv0() {
  asm volatile("s_waitcnt vmcnt(0)" ::: "memory");
  __builtin_amdgcn_sched_barrier(0);
}
__device__ __forceinline__ void sbar() {
  __builtin_amdgcn_s_barrier();
  __builtin_amdgcn_sched_barrier(0);
}

// C(128x128 at m0,n0) += A(MxK row-major bf16) * Bt(NxK row-major bf16)^T
// Each LDS buffer: [A 128x64 | B 128x64] bf16 = 32 KB, XOR-swizzled:
// LDS[row][slot] holds global 16B-chunk (slot ^ (row&7)); frag ds_read_b128
// spreads across all 32 banks. Bit-identical numerics to unswizzled.
// Wave (wr,wc) owns a 64x64 quadrant; 4x4 grid of 16x16x32 MFMA tiles.
__device__ __forceinline__ void gemm_tile(
    const uint16_t* __restrict__ A, int ldA,
    const uint16_t* __restrict__ Bt, int ldB,
    int m0, int n0, int K,
    uint16_t* lds0, uint16_t* lds1, f32x4 acc[4][4])
{
  const int t  = threadIdx.x;
  const int ln = t & 63;
  const int wv = t >> 6;
  const int wr = wv >> 1, wc = wv & 1;

  // thread t stages rows (t>>3)+32c; fetches global chunk gc=(t&7)^(row&7)
  // into LDS slot (t&7). (row+32c)&7 == row&7, so gc is loop-invariant.
  const int row = t >> 3;
  const int gc  = (t & 7) ^ (row & 7);
  const uint16_t* gA = A  + (size_t)(m0 + row) * ldA + (gc << 3);
  const uint16_t* gB = Bt + (size_t)(n0 + row) * ldB + (gc << 3);

  uint16_t* const bufs[2] = { lds0, lds1 };

  auto STAGE = [&](int tile, uint16_t* buf) {
    const uint16_t* ga = gA + tile * BK;
    const uint16_t* gb = gB + tile * BK;
    uint16_t* la = buf + (t << 3);            // 16B*t: lane-contiguous per wave
    uint16_t* lb = buf + BM * BK + (t << 3);
#pragma unroll
    for (int c = 0; c < 4; ++c) {
      gload_lds16(ga + (size_t)(c * 32) * ldA, la + c * 2048);
      gload_lds16(gb + (size_t)(c * 32) * ldB, lb + c * 2048);
    }
  };

  auto COMPUTE = [&](const uint16_t* buf) {
    const uint16_t* bA = buf;
    const uint16_t* bB = buf + BM * BK;
#pragma unroll
    for (int kk = 0; kk < 2; ++kk) {
      const int kc = (kk << 2) + (ln >> 4);     // logical 16B chunk in K
      const int sw = (kc ^ (ln & 7)) << 3;      // swizzled elem offset
      bf16x8 af[4], bfr[4];
#pragma unroll
      for (int mt = 0; mt < 4; ++mt)
        af[mt] = *(const bf16x8*)&bA[((wr << 6) + (mt << 4) + (ln & 15)) * BK + sw];
#pragma unroll
      for (int nt = 0; nt < 4; ++nt)
        bfr[nt] = *(const bf16x8*)&bB[((wc << 6) + (nt << 4) + (ln & 15)) * BK + sw];
      __builtin_amdgcn_s_setprio(1);            // T5: favor MFMA-phase waves
#pragma unroll
      for (int mt = 0; mt < 4; ++mt)
#pragma unroll
        for (int nt = 0; nt < 4; ++nt)
          acc[mt][nt] = __builtin_amdgcn_mfma_f32_16x16x32_bf16(
              af[mt], bfr[nt], acc[mt][nt], 0, 0, 0);
      __builtin_amdgcn_s_setprio(0);
    }
  };

  const int nt = K >> 6;                        // 32 or 16 (always even, >=16)

  // prologue: fill both buffers; wait tile0 only (tile1 keeps flying).
  STAGE(0, bufs[0]);
  STAGE(1, bufs[1]);
  waitv8(); sbar();

  // steady state: 2 barriers/iter, never vmcnt(0).
  for (int i = 0; i < nt - 2; ++i) {
    COMPUTE(bufs[i & 1]);
    sbar();                                     // all waves done reading buf
    STAGE(i + 2, bufs[i & 1]);                  // overwrite with tile i+2
    waitv8(); sbar();                           // tile i+1 landed (FIFO)
  }
  // peel i = nt-2: no more stages; drain for the last tile.
  COMPUTE(bufs[nt & 1]);                        // tile nt-2 (parity (nt-2)&1)
  sbar();
  waitv0(); sbar();                             // tile nt-1 landed
  // peel i = nt-1:
  COMPUTE(bufs[(nt - 1) & 1]);
  sbar();                                       // protect buffers for next call
}

// One Jacobi relaxation step, 3 GEMMs fused in one 640-block grid.
//
// 2-D XCD partition (round 3 — cut HBM fetch 31%): x = b&7; g=x&3 owns the
// bm quarter, h=x>>2 owns the bn half. Per-XCD weight demand 12 MB, state
// slice ~5 MB. Mode-2 (light) blocks dispatched last -> short tail under the
// 2-blocks/CU LDS cap (64 KB).
//
//  j<16  (mode 0): pre0 = s1 @ W0^T            (Bt = W0b native)
//  j<48  (mode 1): pre1 = s2 @ W1^T + s0 @ W0  (pass1 W1b native, pass2 W0Tb)
//  else  (mode 2): pre2 = s1 @ W1              (Bt = W1Tb)
// fp32 masters (in d_out) updated in place; bf16 shadows double-buffered.
__global__ void __launch_bounds__(NTHREADS, 2) step_kernel(
    const uint16_t* __restrict__ s0b_c, const uint16_t* __restrict__ s1b_c,
    const uint16_t* __restrict__ s2b_c,
    uint16_t* __restrict__ s0b_n, uint16_t* __restrict__ s1b_n,
    uint16_t* __restrict__ s2b_n,
    const uint16_t* __restrict__ W0b, const uint16_t* __restrict__ W0Tb,
    const uint16_t* __restrict__ W1b, const uint16_t* __restrict__ W1Tb,
    const float* __restrict__ b0, const float* __restrict__ b1,
    const float* __restrict__ c2f,
    float* __restrict__ s0f, float* __restrict__ s1f, float* __restrict__ s2f)
{
  __shared__ uint16_t lds[2][(BM + BN) * BK];   // 2 x 32 KB double buffer

  f32x4 acc[4][4];
  const f32x4 z = {0.f, 0.f, 0.f, 0.f};
#pragma unroll
  for (int i = 0; i < 4; ++i)
#pragma unroll
    for (int j = 0; j < 4; ++j) acc[i][j] = z;

  const int x = blockIdx.x & 7;    // XCD (dispatch round-robin heuristic)
  const int j = blockIdx.x >> 3;   // 0..79 within XCD
  const int g = x & 3;             // bm-group: bm in {4g..4g+3}
  const int h = x >> 2;            // bn-half
  int mode, bm, bn;
  if (j < 16) {
    mode = 0; bm = (g << 2) + (j >> 2); bn = (h << 2) + (j & 3);
    gemm_tile(s1b_c, 2048, W0b, 2048, bm * BM, bn * BN, 2048, lds[0], lds[1], acc);
  } else if (j < 48) {
    mode = 1; const int u = j - 16; bm = (g << 2) + (u >> 3); bn = (h << 3) + (u & 7);
    gemm_tile(s2b_c, 2048, W1b, 2048, bm * BM, bn * BN, 2048, lds[0], lds[1], acc);
    gemm_tile(s0b_c, 1024, W0Tb, 1024, bm * BM, bn * BN, 1024, lds[0], lds[1], acc);
  } else {
    mode = 2; const int u = j - 48; bm = (g << 2) + (u >> 3); bn = (h << 3) + (u & 7);
    gemm_tile(s1b_c, 2048, W1Tb, 2048, bm * BM, bn * BN, 2048, lds[0], lds[1], acc);
  }

  const int t = threadIdx.x, wv = t >> 6, ln = t & 63;
  const int wr = wv >> 1, wc = wv & 1;
  const int rb = (ln >> 4) << 2, cc = ln & 15;
  const int m0 = bm * BM, n0 = bn * BN;

#pragma unroll
  for (int mt = 0; mt < 4; ++mt) {
#pragma unroll
    for (int nt = 0; nt < 4; ++nt) {
      const int gn = n0 + (wc << 6) + (nt << 4) + cc;
      float add = 0.f;
      if (mode == 0) add = b0[gn];
      else if (mode == 1) add = b1[gn];
#pragma unroll
      for (int r = 0; r < 4; ++r) {
        const int gm = m0 + (wr << 6) + (mt << 4) + rb + r;
        const float pre = acc[mt][nt][r];
        if (mode == 0) {
          const size_t ix = (size_t)gm * 1024 + gn;
          float nv = 0.8f * s0f[ix] + 0.2f * (pre + add);
          nv = fminf(fmaxf(nv, 0.f), 1.f);
          s0f[ix] = nv;
          s0b_n[ix] = f2bf(nv);
        } else if (mode == 1) {
          const size_t ix = (size_t)gm * 2048 + gn;
          float nv = 0.8f * s1f[ix] + 0.2f * (pre + add);
          nv = fminf(fmaxf(nv, 0.f), 1.f);
          s1f[ix] = nv;
          s1b_n[ix] = f2bf(nv);
        } else {
          const size_t ix = (size_t)gm * 2048 + gn;
          float nv = 0.8f * s2f[ix] + 0.2f * (pre + c2f[ix]);
          nv = fminf(fmaxf(nv, 0.f), 1.f);
          s2f[ix] = nv;
          s2b_n[ix] = f2bf(nv);
        }
      }
    }
  }
}

// c2 = data @ W2^T + b2 (step-invariant), fp32 result.
__global__ void __launch_bounds__(NTHREADS, 2) c2_kernel(
    const uint16_t* __restrict__ datab,
    const uint16_t* __restrict__ W2b,
    const float* __restrict__ b2,
    float* __restrict__ c2f)
{
  __shared__ uint16_t lds[2][(BM + BN) * BK];
  f32x4 acc[4][4];
  const f32x4 z = {0.f, 0.f, 0.f, 0.f};
#pragma unroll
  for (int i = 0; i < 4; ++i)
#pragma unroll
    for (int j = 0; j < 4; ++j) acc[i][j] = z;

  const int bm = blockIdx.x >> 4, bn = blockIdx.x & 15;
  gemm_tile(datab, 2048, W2b, 2048, bm * BM, bn * BN, 2048, lds[0], lds[1], acc);

  const int t = threadIdx.x, wv = t >> 6, ln = t & 63;
  const int wr = wv >> 1, wc = wv & 1;
  const int rb = (ln >> 4) << 2, cc = ln & 15;
  const int m0 = bm * BM, n0 = bn * BN;
#pragma unroll
  for (int mt = 0; mt < 4; ++mt)
#pragma unroll
    for (int nt = 0; nt < 4; ++nt) {
      const int gn = n0 + (wc << 6) + (nt << 4) + cc;
      const float bb = b2[gn];
#pragma unroll
      for (int r = 0; r < 4; ++r) {
        const int gm = m0 + (wr << 6) + (mt << 4) + rb + r;
        c2f[(size_t)gm * 2048 + gn] = acc[mt][nt][r] + bb;
      }
    }
}

// fp32 -> bf16 straight convert, 4 elems/thread.
__global__ void conv_k(const float* __restrict__ src, uint16_t* __restrict__ dst)
{
  const size_t i4 = ((size_t)blockIdx.x * 256 + threadIdx.x) << 2;
  const float4 v = *(const float4*)(src + i4);
  ushort4 o;
  o.x = f2bf(v.x); o.y = f2bf(v.y); o.z = f2bf(v.z); o.w = f2bf(v.w);
  *(ushort4*)(dst + i4) = o;
}

// fp32 -> bf16 transposed: dst[c*ldD + r] = bf16(src[r*ldS + c]).
__global__ void convT_k(const float* __restrict__ src, uint16_t* __restrict__ dst,
                        int ldS, int ldD)
{
  __shared__ uint16_t tile[32][33];
  const int r0 = blockIdx.y * 32, c0 = blockIdx.x * 32;
  tile[threadIdx.y][threadIdx.x] =
      f2bf(src[(size_t)(r0 + threadIdx.y) * ldS + c0 + threadIdx.x]);
  __syncthreads();
  dst[(size_t)(c0 + threadIdx.y) * ldD + r0 + threadIdx.x] = tile[threadIdx.x][threadIdx.y];
}

// fp32 input -> fp32 master (in d_out) + bf16 shadow. 4 elems/thread.
__global__ void init_state(const float* __restrict__ in,
                           float* __restrict__ sf, uint16_t* __restrict__ sb)
{
  const size_t i4 = ((size_t)blockIdx.x * 256 + threadIdx.x) << 2;
  const float4 v = *(const float4*)(in + i4);
  *(float4*)(sf + i4) = v;
  ushort4 o;
  o.x = f2bf(v.x); o.y = f2bf(v.y); o.z = f2bf(v.z); o.w = f2bf(v.w);
  *(ushort4*)(sb + i4) = o;
}

extern "C" void kernel_launch(void* const* d_in, const int* in_sizes, int n_in,
                              void* d_out, int out_size, void* d_ws, size_t ws_size,
                              hipStream_t stream) {
  const float* s0   = (const float*)d_in[0];
  const float* s1   = (const float*)d_in[1];
  const float* s2   = (const float*)d_in[2];
  const float* data = (const float*)d_in[3];
  const float* W0   = (const float*)d_in[4];
  const float* b0   = (const float*)d_in[5];
  const float* W1   = (const float*)d_in[6];
  const float* b1   = (const float*)d_in[7];
  const float* W2   = (const float*)d_in[8];
  const float* b2   = (const float*)d_in[9];

  // fp32 masters live directly in d_out: [s0 | s1 | s2].
  float* s0f = (float*)d_out;
  float* s1f = s0f + 2048ull * 1024;
  float* s2f = s1f + 2048ull * 2048;

  char* ws = (char*)d_ws;
  size_t off = 0;
  auto alloc = [&](size_t bytes) -> char* {
    char* p = ws + off; off += (bytes + 255) & ~(size_t)255; return p;
  };
  uint16_t* W0b    = (uint16_t*)alloc(1024ull * 2048 * 2);
  uint16_t* W0Tb   = (uint16_t*)alloc(2048ull * 1024 * 2);
  uint16_t* W1b    = (uint16_t*)alloc(2048ull * 2048 * 2);
  uint16_t* W1Tb   = (uint16_t*)alloc(2048ull * 2048 * 2);
  float*    c2f    = (float*)   alloc(2048ull * 2048 * 4);
  uint16_t* s0b[2] = { (uint16_t*)alloc(2048ull * 1024 * 2),
                       (uint16_t*)alloc(2048ull * 1024 * 2) };
  uint16_t* s1b[2] = { (uint16_t*)alloc(2048ull * 2048 * 2),
                       (uint16_t*)alloc(2048ull * 2048 * 2) };
  uint16_t* s2b[2] = { (uint16_t*)alloc(2048ull * 2048 * 2),
                       (uint16_t*)alloc(2048ull * 2048 * 2) };
  (void)ws_size; (void)in_sizes; (void)n_in; (void)out_size;

  // --- one-time weight prep (fp32 -> bf16) ---
  conv_k<<<1024 * 2048 / 1024, 256, 0, stream>>>(W0, W0b);
  conv_k<<<2048 * 2048 / 1024, 256, 0, stream>>>(W1, W1b);
  dim3 tb(32, 32);
  convT_k<<<dim3(64, 32), tb, 0, stream>>>(W0, W0Tb, 2048, 1024);
  convT_k<<<dim3(64, 64), tb, 0, stream>>>(W1, W1Tb, 2048, 2048);
  // data, W2 -> bf16 into step-"next" shadow buffers (fully overwritten by step 0
  // epilogue before step 1 reads them — safe temps).
  conv_k<<<2048 * 2048 / 1024, 256, 0, stream>>>(data, s1b[1]);
  conv_k<<<2048 * 2048 / 1024, 256, 0, stream>>>(W2, s2b[1]);
  c2_kernel<<<256, NTHREADS, 0, stream>>>(s1b[1], s2b[1], b2, c2f);

  // --- state init: fp32 masters (in d_out) + bf16 shadows ---
  init_state<<<2048 * 1024 / 1024, 256, 0, stream>>>(s0, s0f, s0b[0]);
  init_state<<<2048 * 2048 / 1024, 256, 0, stream>>>(s1, s1f, s1b[0]);
  init_state<<<2048 * 2048 / 1024, 256, 0, stream>>>(s2, s2f, s2b[0]);

  // --- 30 Jacobi relaxation steps, double-buffered bf16 shadows ---
  for (int it = 0; it < 30; ++it) {
    const int c = it & 1, n = c ^ 1;
    step_kernel<<<640, NTHREADS, 0, stream>>>(
        s0b[c], s1b[c], s2b[c], s0b[n], s1b[n], s2b[n],
        W0b, W0Tb, W1b, W1Tb, b0, b1, c2f, s0f, s1f, s2f);
  }
  // masters already in d_out — no output kernel needed.
}

// Round 7
// 2836.709 us; speedup vs baseline: 1.2956x; 1.2956x over previous
//
#include <hip/hip_runtime.h>
#include <stdint.h>

// 128x128 block tile, 4 waves (256 threads), per-wave 64x64 (proven geometry).
// Round 7: 3-slot rotating LDS pipeline at BK=32 with counted vmcnt(4).
//   iter i: STAGE(i+2 -> slot[(i+2)%3]) ; COMPUTE(slot[i%3]) ; vmcnt(4) ; bar
// Race-free by construction: slot written at i+2 was last read at iter i,
// separated by >=2 barriers; vmcnt(4) (FIFO, m135) guarantees stage(i+1)
// landed while stage(i+2)'s 4 loads stay in flight across the barrier.
// Loads get ~1.5 iters (~300cy) of MFMA cover vs 0 in the 2-phase drain
// (m233: that drain = 72% of critical path; our 614 TF == its 607 ceiling).
// LDS 3x16KB = 48KB -> 3 blocks/CU cap, residency unchanged vs baseline
// (fixes R6's occupancy cut). Numerics bit-identical to the verified kernel.
#define BM 128
#define BN 128
#define BK 32
#define NTHREADS 256
#define SLOT_ELEMS 8192          // (128*32 A + 128*32 B) bf16 elems = 16 KB

typedef __bf16 bf16x8 __attribute__((ext_vector_type(8)));
typedef float f32x4 __attribute__((ext_vector_type(4)));

__device__ __forceinline__ float bf2f(uint16_t u) {
  union { uint32_t u32; float f; } x; x.u32 = ((uint32_t)u) << 16; return x.f;
}
// round-to-nearest-even f32 -> bf16 (finite values only)
__device__ __forceinline__ uint16_t f2bf(float f) {
  uint32_t x = __float_as_uint(f);
  uint32_t r = (x + 0x7FFFu + ((x >> 16) & 1u)) >> 16;
  return (uint16_t)r;
}

// async global->LDS, 16B per lane. LDS dest is wave-uniform base + lane*16B.
__device__ __forceinline__ void gload_lds16(const uint16_t* g, uint16_t* l) {
  __builtin_amdgcn_global_load_lds(
      (const __attribute__((address_space(1))) uint32_t*)g,
      (__attribute__((address_space(3))) uint32_t*)l, 16, 0, 0);
}

// counted waits + raw barrier; sched_barrier(0) pins the boundary (rule #18).
__device__ __forceinline__ void waitv4() {
  asm volatile("s_waitcnt vmcnt(4)" ::: "memory");
  __builtin_amdgcn_sched_barrier(0);
}
__device__ __forceinline__ void waitv0() {
  asm volatile("s_waitcnt vmcnt(0)" ::: "memory");
  __builtin_amdgcn_sched_barrier(0);
}
__device__ __forceinline__ void sbar() {
  __builtin_amdgcn_s_barrier();
  __builtin_amdgcn_sched_barrier(0);
}

// C(128x128 at m0,n0) += A(MxK row-major bf16) * Bt(NxK row-major bf16)^T
// BK=32: rows are 4 x 16B chunks. XOR swizzle: LDS[row][slot] holds global
// chunk (slot ^ (row&3)); read addr uses sw = (kc ^ (ln&3))*8 with kc=ln>>4.
// Balanced banks: per b128 wave-op each bank gets exactly 8 x 4B accesses.
// Staging: thread t -> row t>>2 (+64 per round), chunk slot t&3, global chunk
// gc = (t&3)^(row&3); (row+64)&3 == row&3 so gc is round-invariant. LDS dest
// (t*16B) is lane-contiguous per wave as gload_lds requires.
__device__ __forceinline__ void gemm_tile(
    const uint16_t* __restrict__ A, int ldA,
    const uint16_t* __restrict__ Bt, int ldB,
    int m0, int n0, int K,
    uint16_t* lds, f32x4 acc[4][4])
{
  const int t  = threadIdx.x;
  const int ln = t & 63;
  const int wv = t >> 6;
  const int wr = wv >> 1, wc = wv & 1;

  const int row = t >> 2;                 // 0..63
  const int gc  = (t & 3) ^ (row & 3);
  const uint16_t* gA = A  + (size_t)(m0 + row) * ldA + (gc << 3);
  const uint16_t* gB = Bt + (size_t)(n0 + row) * ldB + (gc << 3);

  auto STAGE = [&](int kt, int s) {
    uint16_t* base = lds + s * SLOT_ELEMS;
    const uint16_t* ga = gA + kt * BK;
    const uint16_t* gb = gB + kt * BK;
    uint16_t* la = base + (t << 3);       // A region: rows 0..63 then 64..127
    uint16_t* lb = base + 4096 + (t << 3);
    gload_lds16(ga,                       la);
    gload_lds16(ga + (size_t)64 * ldA,    la + 2048);
    gload_lds16(gb,                       lb);
    gload_lds16(gb + (size_t)64 * ldB,    lb + 2048);
  };

  const int sw = (((ln >> 4) ^ (ln & 3)) << 3);   // swizzled elem offset

  auto COMPUTE = [&](int s) {
    const uint16_t* bA = lds + s * SLOT_ELEMS;
    const uint16_t* bB = bA + 4096;
    bf16x8 af[4], bfr[4];
#pragma unroll
    for (int mt = 0; mt < 4; ++mt)
      af[mt] = *(const bf16x8*)&bA[((wr << 6) + (mt << 4) + (ln & 15)) * BK + sw];
#pragma unroll
    for (int nt = 0; nt < 4; ++nt)
      bfr[nt] = *(const bf16x8*)&bB[((wc << 6) + (nt << 4) + (ln & 15)) * BK + sw];
    __builtin_amdgcn_s_setprio(1);        // T5: pipeline creates role diversity
#pragma unroll
    for (int mt = 0; mt < 4; ++mt)
#pragma unroll
      for (int nt = 0; nt < 4; ++nt)
        acc[mt][nt] = __builtin_amdgcn_mfma_f32_16x16x32_bf16(
            af[mt], bfr[nt], acc[mt][nt], 0, 0, 0);
    __builtin_amdgcn_s_setprio(0);
  };

  const int nt = K >> 5;                  // 32 or 64 K-tiles (>= 3)

  // prologue: fill slots 0,1; wait own stage(0) (4 oldest), then barrier
  // propagates "everyone's stage(0) landed" across the block.
  STAGE(0, 0);
  STAGE(1, 1);
  waitv4(); sbar();

  int sc = 0, sn = 1, sf = 2;             // compute / next / fill slots
  for (int i = 0; i < nt - 2; ++i) {
    STAGE(i + 2, sf);                     // issue first: max cover under MFMA
    COMPUTE(sc);
    waitv4(); sbar();                     // stage(i+1) landed; slot sc free
    const int tmp = sc; sc = sn; sn = sf; sf = tmp;
  }
  COMPUTE(sc);                            // tile nt-2
  waitv0(); sbar();                       // last tile fully landed (all waves)
  COMPUTE(sn);                            // tile nt-1
  sbar();                                 // protect slots for next call
}

// One Jacobi relaxation step, 3 GEMMs fused in one 640-block grid.
//
// 2-D XCD partition (round 3 — cut HBM fetch 31%): x = b&7; g=x&3 owns the
// bm quarter, h=x>>2 owns the bn half. Per-XCD weight demand 12 MB, state
// slice ~5 MB.
//
//  j<16  (mode 0): pre0 = s1 @ W0^T            (Bt = W0b native)
//  j<48  (mode 1): pre1 = s2 @ W1^T + s0 @ W0  (pass1 W1b native, pass2 W0Tb)
//  else  (mode 2): pre2 = s1 @ W1              (Bt = W1Tb)
// fp32 masters (in d_out) updated in place; bf16 shadows double-buffered.
__global__ void __launch_bounds__(NTHREADS, 3) step_kernel(
    const uint16_t* __restrict__ s0b_c, const uint16_t* __restrict__ s1b_c,
    const uint16_t* __restrict__ s2b_c,
    uint16_t* __restrict__ s0b_n, uint16_t* __restrict__ s1b_n,
    uint16_t* __restrict__ s2b_n,
    const uint16_t* __restrict__ W0b, const uint16_t* __restrict__ W0Tb,
    const uint16_t* __restrict__ W1b, const uint16_t* __restrict__ W1Tb,
    const float* __restrict__ b0, const float* __restrict__ b1,
    const float* __restrict__ c2f,
    float* __restrict__ s0f, float* __restrict__ s1f, float* __restrict__ s2f)
{
  __shared__ uint16_t lds[3 * SLOT_ELEMS];   // 48 KB -> 3 blocks/CU cap

  f32x4 acc[4][4];
  const f32x4 z = {0.f, 0.f, 0.f, 0.f};
#pragma unroll
  for (int i = 0; i < 4; ++i)
#pragma unroll
    for (int j = 0; j < 4; ++j) acc[i][j] = z;

  const int x = blockIdx.x & 7;    // XCD (dispatch round-robin heuristic)
  const int j = blockIdx.x >> 3;   // 0..79 within XCD
  const int g = x & 3;             // bm-group: bm in {4g..4g+3}
  const int h = x >> 2;            // bn-half
  int mode, bm, bn;
  if (j < 16) {
    mode = 0; bm = (g << 2) + (j >> 2); bn = (h << 2) + (j & 3);
    gemm_tile(s1b_c, 2048, W0b, 2048, bm * BM, bn * BN, 2048, lds, acc);
  } else if (j < 48) {
    mode = 1; const int u = j - 16; bm = (g << 2) + (u >> 3); bn = (h << 3) + (u & 7);
    gemm_tile(s2b_c, 2048, W1b, 2048, bm * BM, bn * BN, 2048, lds, acc);
    gemm_tile(s0b_c, 1024, W0Tb, 1024, bm * BM, bn * BN, 1024, lds, acc);
  } else {
    mode = 2; const int u = j - 48; bm = (g << 2) + (u >> 3); bn = (h << 3) + (u & 7);
    gemm_tile(s1b_c, 2048, W1Tb, 2048, bm * BM, bn * BN, 2048, lds, acc);
  }

  const int t = threadIdx.x, wv = t >> 6, ln = t & 63;
  const int wr = wv >> 1, wc = wv & 1;
  const int rb = (ln >> 4) << 2, cc = ln & 15;
  const int m0 = bm * BM, n0 = bn * BN;

#pragma unroll
  for (int mt = 0; mt < 4; ++mt) {
#pragma unroll
    for (int nt = 0; nt < 4; ++nt) {
      const int gn = n0 + (wc << 6) + (nt << 4) + cc;
      float add = 0.f;
      if (mode == 0) add = b0[gn];
      else if (mode == 1) add = b1[gn];
#pragma unroll
      for (int r = 0; r < 4; ++r) {
        const int gm = m0 + (wr << 6) + (mt << 4) + rb + r;
        const float pre = acc[mt][nt][r];
        if (mode == 0) {
          const size_t ix = (size_t)gm * 1024 + gn;
          float nv = 0.8f * s0f[ix] + 0.2f * (pre + add);
          nv = fminf(fmaxf(nv, 0.f), 1.f);
          s0f[ix] = nv;
          s0b_n[ix] = f2bf(nv);
        } else if (mode == 1) {
          const size_t ix = (size_t)gm * 2048 + gn;
          float nv = 0.8f * s1f[ix] + 0.2f * (pre + add);
          nv = fminf(fmaxf(nv, 0.f), 1.f);
          s1f[ix] = nv;
          s1b_n[ix] = f2bf(nv);
        } else {
          const size_t ix = (size_t)gm * 2048 + gn;
          float nv = 0.8f * s2f[ix] + 0.2f * (pre + c2f[ix]);
          nv = fminf(fmaxf(nv, 0.f), 1.f);
          s2f[ix] = nv;
          s2b_n[ix] = f2bf(nv);
        }
      }
    }
  }
}

// c2 = data @ W2^T + b2 (step-invariant), fp32 result.
__global__ void __launch_bounds__(NTHREADS, 3) c2_kernel(
    const uint16_t* __restrict__ datab,
    const uint16_t* __restrict__ W2b,
    const float* __restrict__ b2,
    float* __restrict__ c2f)
{
  __shared__ uint16_t lds[3 * SLOT_ELEMS];
  f32x4 acc[4][4];
  const f32x4 z = {0.f, 0.f, 0.f, 0.f};
#pragma unroll
  for (int i = 0; i < 4; ++i)
#pragma unroll
    for (int j = 0; j < 4; ++j) acc[i][j] = z;

  const int bm = blockIdx.x >> 4, bn = blockIdx.x & 15;
  gemm_tile(datab, 2048, W2b, 2048, bm * BM, bn * BN, 2048, lds, acc);

  const int t = threadIdx.x, wv = t >> 6, ln = t & 63;
  const int wr = wv >> 1, wc = wv & 1;
  const int rb = (ln >> 4) << 2, cc = ln & 15;
  const int m0 = bm * BM, n0 = bn * BN;
#pragma unroll
  for (int mt = 0; mt < 4; ++mt)
#pragma unroll
    for (int nt = 0; nt < 4; ++nt) {
      const int gn = n0 + (wc << 6) + (nt << 4) + cc;
      const float bb = b2[gn];
#pragma unroll
      for (int r = 0; r < 4; ++r) {
        const int gm = m0 + (wr << 6) + (mt << 4) + rb + r;
        c2f[(size_t)gm * 2048 + gn] = acc[mt][nt][r] + bb;
      }
    }
}

// fp32 -> bf16 straight convert, 4 elems/thread.
__global__ void conv_k(const float* __restrict__ src, uint16_t* __restrict__ dst)
{
  const size_t i4 = ((size_t)blockIdx.x * 256 + threadIdx.x) << 2;
  const float4 v = *(const float4*)(src + i4);
  ushort4 o;
  o.x = f2bf(v.x); o.y = f2bf(v.y); o.z = f2bf(v.z); o.w = f2bf(v.w);
  *(ushort4*)(dst + i4) = o;
}

// fp32 -> bf16 transposed: dst[c*ldD + r] = bf16(src[r*ldS + c]).
__global__ void convT_k(const float* __restrict__ src, uint16_t* __restrict__ dst,
                        int ldS, int ldD)
{
  __shared__ uint16_t tile[32][33];
  const int r0 = blockIdx.y * 32, c0 = blockIdx.x * 32;
  tile[threadIdx.y][threadIdx.x] =
      f2bf(src[(size_t)(r0 + threadIdx.y) * ldS + c0 + threadIdx.x]);
  __syncthreads();
  dst[(size_t)(c0 + threadIdx.y) * ldD + r0 + threadIdx.x] = tile[threadIdx.x][threadIdx.y];
}

// fp32 input -> fp32 master (in d_out) + bf16 shadow. 4 elems/thread.
__global__ void init_state(const float* __restrict__ in,
                           float* __restrict__ sf, uint16_t* __restrict__ sb)
{
  const size_t i4 = ((size_t)blockIdx.x * 256 + threadIdx.x) << 2;
  const float4 v = *(const float4*)(in + i4);
  *(float4*)(sf + i4) = v;
  ushort4 o;
  o.x = f2bf(v.x); o.y = f2bf(v.y); o.z = f2bf(v.z); o.w = f2bf(v.w);
  *(ushort4*)(sb + i4) = o;
}

extern "C" void kernel_launch(void* const* d_in, const int* in_sizes, int n_in,
                              void* d_out, int out_size, void* d_ws, size_t ws_size,
                              hipStream_t stream) {
  const float* s0   = (const float*)d_in[0];
  const float* s1   = (const float*)d_in[1];
  const float* s2   = (const float*)d_in[2];
  const float* data = (const float*)d_in[3];
  const float* W0   = (const float*)d_in[4];
  const float* b0   = (const float*)d_in[5];
  const float* W1   = (const float*)d_in[6];
  const float* b1   = (const float*)d_in[7];
  const float* W2   = (const float*)d_in[8];
  const float* b2   = (const float*)d_in[9];

  // fp32 masters live directly in d_out: [s0 | s1 | s2].
  float* s0f = (float*)d_out;
  float* s1f = s0f + 2048ull * 1024;
  float* s2f = s1f + 2048ull * 2048;

  char* ws = (char*)d_ws;
  size_t off = 0;
  auto alloc = [&](size_t bytes) -> char* {
    char* p = ws + off; off += (bytes + 255) & ~(size_t)255; return p;
  };
  uint16_t* W0b    = (uint16_t*)alloc(1024ull * 2048 * 2);
  uint16_t* W0Tb   = (uint16_t*)alloc(2048ull * 1024 * 2);
  uint16_t* W1b    = (uint16_t*)alloc(2048ull * 2048 * 2);
  uint16_t* W1Tb   = (uint16_t*)alloc(2048ull * 2048 * 2);
  float*    c2f    = (float*)   alloc(2048ull * 2048 * 4);
  uint16_t* s0b[2] = { (uint16_t*)alloc(2048ull * 1024 * 2),
                       (uint16_t*)alloc(2048ull * 1024 * 2) };
  uint16_t* s1b[2] = { (uint16_t*)alloc(2048ull * 2048 * 2),
                       (uint16_t*)alloc(2048ull * 2048 * 2) };
  uint16_t* s2b[2] = { (uint16_t*)alloc(2048ull * 2048 * 2),
                       (uint16_t*)alloc(2048ull * 2048 * 2) };
  (void)ws_size; (void)in_sizes; (void)n_in; (void)out_size;

  // --- one-time weight prep (fp32 -> bf16) ---
  conv_k<<<1024 * 2048 / 1024, 256, 0, stream>>>(W0, W0b);
  conv_k<<<2048 * 2048 / 1024, 256, 0, stream>>>(W1, W1b);
  dim3 tb(32, 32);
  convT_k<<<dim3(64, 32), tb, 0, stream>>>(W0, W0Tb, 2048, 1024);
  convT_k<<<dim3(64, 64), tb, 0, stream>>>(W1, W1Tb, 2048, 2048);
  // data, W2 -> bf16 into step-"next" shadow buffers (fully overwritten by step 0
  // epilogue before step 1 reads them — safe temps).
  conv_k<<<2048 * 2048 / 1024, 256, 0, stream>>>(data, s1b[1]);
  conv_k<<<2048 * 2048 / 1024, 256, 0, stream>>>(W2, s2b[1]);
  c2_kernel<<<256, NTHREADS, 0, stream>>>(s1b[1], s2b[1], b2, c2f);

  // --- state init: fp32 masters (in d_out) + bf16 shadows ---
  init_state<<<2048 * 1024 / 1024, 256, 0, stream>>>(s0, s0f, s0b[0]);
  init_state<<<2048 * 2048 / 1024, 256, 0, stream>>>(s1, s1f, s1b[0]);
  init_state<<<2048 * 2048 / 1024, 256, 0, stream>>>(s2, s2f, s2b[0]);

  // --- 30 Jacobi relaxation steps, double-buffered bf16 shadows ---
  for (int it = 0; it < 30; ++it) {
    const int c = it & 1, n = c ^ 1;
    step_kernel<<<640, NTHREADS, 0, stream>>>(
        s0b[c], s1b[c], s2b[c], s0b[n], s1b[n], s2b[n],
        W0b, W0Tb, W1b, W1Tb, b0, b1, c2f, s0f, s1f, s2f);
  }
  // masters already in d_out — no output kernel needed.
}